// Round 7
// baseline (439.629 us; speedup 1.0000x reference)
//
#include <hip/hip_runtime.h>
#include <math.h>

#define B_   24
#define NA_  50
#define T_   10
#define NV_  196
#define D_   512
#define M_   1200          // B*NA audio rows
#define MPAD 1280          // padded to 20 tiles of 64
#define NVP  224           // 196 padded to 14*16
#define NVH  112           // half-tile of cols (one wave-item)
#define YT_  240           // B*T
#define VROWS (YT_ * NVP)  // 53760 padded visual rows

typedef __bf16 bf16x8 __attribute__((ext_vector_type(8)));
typedef float  f32x4  __attribute__((ext_vector_type(4)));
typedef unsigned short ushort8 __attribute__((ext_vector_type(8)));

__device__ __forceinline__ unsigned short f2bf(float f) {
    unsigned u = __float_as_uint(f);
    u += 0x7FFF + ((u >> 16) & 1);       // RNE
    return (unsigned short)(u >> 16);
}

__device__ __forceinline__ void gload16(const void* g, void* l) {
    __builtin_amdgcn_global_load_lds(
        (const __attribute__((address_space(1))) unsigned int*)g,
        (__attribute__((address_space(3))) unsigned int*)l, 16, 0, 0);
}

// ---- merged: L2-normalize + bf16 convert for V and A; also zero-inits accs ----
__global__ void normconv_kernel(const float* __restrict__ vf, const float* __restrict__ af,
                                const float* __restrict__ tempPtr,
                                unsigned short* __restrict__ Vbf, unsigned short* __restrict__ Abf,
                                float* __restrict__ accs) {
    if (blockIdx.x == 0 && threadIdx.x < 3) accs[threadIdx.x] = 0.0f;
    int w = threadIdx.x >> 6, lane = threadIdx.x & 63;
    int row = blockIdx.x * 4 + w;
    const float* p = nullptr;
    unsigned short* dstp;
    float tscale = 1.0f;
    if (row < VROWS) {
        int yt = row / NVP, vv = row - yt * NVP;
        dstp = Vbf + (size_t)row * D_;
        if (vv < NV_) p = vf + ((size_t)yt * NV_ + vv) * D_;
    } else {
        int ar = row - VROWS;
        if (ar >= MPAD) return;
        dstp = Abf + (size_t)ar * D_;
        if (ar < M_) { p = af + (size_t)ar * D_; tscale = tempPtr[0]; }
    }
    ushort8* dst = (ushort8*)(dstp + lane * 8);
    if (p) {
        float4 u = *(const float4*)(p + lane * 8);
        float4 v = *(const float4*)(p + lane * 8 + 4);
        float s = u.x*u.x + u.y*u.y + u.z*u.z + u.w*u.w
                + v.x*v.x + v.y*v.y + v.z*v.z + v.w*v.w;
        #pragma unroll
        for (int off = 32; off; off >>= 1) s += __shfl_xor(s, off, 64);
        float sc = 1.0f / (fmaxf(sqrtf(s), 1e-12f) * tscale);
        ushort8 o;
        o[0]=f2bf(u.x*sc); o[1]=f2bf(u.y*sc); o[2]=f2bf(u.z*sc); o[3]=f2bf(u.w*sc);
        o[4]=f2bf(v.x*sc); o[5]=f2bf(v.y*sc); o[6]=f2bf(v.z*sc); o[7]=f2bf(v.w*sc);
        *dst = o;
    } else {
        ushort8 z = (ushort8)0;
        *dst = z;
    }
}

// ---- barrier-free MFMA GEMM + fused max/clip reductions ----
// grid: 480 = 8 XCDs x (20 rt x 3 reps). Block: 256 (4 independent waves).
// Block stages its A-tile (64 rows x K=512, 64 KB) in LDS ONCE (single barrier).
// Each wave then processes 5 (yt, col-half) items: 64x112 tile, acc[4][7],
// B-fragments streamed global->VGPR (L2-resident, XCD-local), double-buffered.
// NO __syncthreads in the K-loop -> no vmcnt(0) drain; loads fly under MFMA.
// LDS A layout: chunk-major units: chunk c (32 k) at c*4096, row-block rb at
// +rb*1024, lane (q,m16) at +lane*16 -> conflict-free ds_read_b128.
__global__ __launch_bounds__(256, 2) void simred_kernel(
    const unsigned short* __restrict__ Abf, const unsigned short* __restrict__ Vbf,
    float* __restrict__ maxvisH, float* __restrict__ accNonneg)
{
    __shared__ __align__(16) unsigned char lds[65536];

    const int tid  = threadIdx.x;
    const int lane = tid & 63;
    const int w    = tid >> 6;
    const int q    = lane >> 4;
    const int m16  = lane & 15;

    const int bid  = blockIdx.x;
    const int xcd  = bid & 7;          // dispatch heuristic: round-robin XCD
    const int s    = bid >> 3;         // 0..59
    const int rt   = s % 20;
    const int rep  = s / 20;           // 0..2
    const int widx = rep * 4 + w;      // 0..11 (wave index within (xcd, rt))
    const int rowA0 = rt * 64;

    // ---- one-time A staging: 16 DMA loads per thread ----
    #pragma unroll
    for (int i = 0; i < 16; ++i) {
        int u = w * 16 + i;            // unit 0..63
        int c = u >> 2, rb = u & 3;
        const unsigned short* g = Abf + (size_t)(rowA0 + rb * 16 + m16) * D_ + c * 32 + q * 8;
        gload16(g, lds + u * 1024);
    }
    __syncthreads();                   // only barrier in the kernel

    float cs = 0.0f;                   // clip(s,-20,0)^2 accumulator across items

    #pragma unroll 1
    for (int it = 0; it < 5; ++it) {
        const int e    = widx + 12 * it;   // 0..59
        const int ytl  = e >> 1;
        const int half = e & 1;
        const int yt   = xcd * 30 + ytl;
        // B-frag base: row (=col n) m16, k-piece q (verified layout)
        const unsigned short* vb =
            Vbf + ((size_t)yt * NVP + half * NVH + m16) * D_ + q * 8;

        f32x4 acc[4][7];
        #pragma unroll
        for (int i = 0; i < 4; ++i)
            #pragma unroll
            for (int j = 0; j < 7; ++j) acc[i][j] = (f32x4)0.0f;

        bf16x8 bA[7], bB[7];
        #pragma unroll
        for (int j = 0; j < 7; ++j) bA[j] = *(const bf16x8*)(vb + (size_t)j * 16 * D_);

        #pragma unroll
        for (int cc = 0; cc < 8; ++cc) {
            // ---- chunk 2cc: compute with bA, prefetch 2cc+1 into bB ----
            #pragma unroll
            for (int j = 0; j < 7; ++j)
                bB[j] = *(const bf16x8*)(vb + (size_t)j * 16 * D_ + (2 * cc + 1) * 32);
            {
                bf16x8 af[4];
                #pragma unroll
                for (int i = 0; i < 4; ++i)
                    af[i] = *(const bf16x8*)(lds + (2 * cc) * 4096 + i * 1024 + lane * 16);
                #pragma unroll
                for (int i = 0; i < 4; ++i)
                    #pragma unroll
                    for (int j = 0; j < 7; ++j)
                        acc[i][j] = __builtin_amdgcn_mfma_f32_16x16x32_bf16(af[i], bA[j], acc[i][j], 0, 0, 0);
            }
            // ---- chunk 2cc+1: compute with bB, prefetch 2cc+2 into bA ----
            if (cc < 7) {
                #pragma unroll
                for (int j = 0; j < 7; ++j)
                    bA[j] = *(const bf16x8*)(vb + (size_t)j * 16 * D_ + (2 * cc + 2) * 32);
            }
            {
                bf16x8 af[4];
                #pragma unroll
                for (int i = 0; i < 4; ++i)
                    af[i] = *(const bf16x8*)(lds + (2 * cc + 1) * 4096 + i * 1024 + lane * 16);
                #pragma unroll
                for (int i = 0; i < 4; ++i)
                    #pragma unroll
                    for (int j = 0; j < 7; ++j)
                        acc[i][j] = __builtin_amdgcn_mfma_f32_16x16x32_bf16(af[i], bB[j], acc[i][j], 0, 0, 0);
            }
        }

        // ---- clip-sum (zero-padded rows/cols contribute exactly 0) ----
        #pragma unroll
        for (int i = 0; i < 4; ++i)
            #pragma unroll
            for (int j = 0; j < 7; ++j)
                #pragma unroll
                for (int r = 0; r < 4; ++r) {
                    float v = acc[i][j][r];
                    float cv = fminf(fmaxf(v, -20.0f), 0.0f);
                    cs += cv * cv;
                }

        // ---- per-row max over this half's valid cols ----
        // col = half*112 + j*16 + m16; valid iff < 196
        bool colv[7];
        #pragma unroll
        for (int j = 0; j < 7; ++j) colv[j] = (half * NVH + j * 16 + m16) < NV_;
        const int y = yt / T_, t = yt - (yt / T_) * T_;
        #pragma unroll
        for (int i = 0; i < 4; ++i) {
            float mx[4] = {-3e38f, -3e38f, -3e38f, -3e38f};
            #pragma unroll
            for (int j = 0; j < 7; ++j)
                #pragma unroll
                for (int r = 0; r < 4; ++r)
                    mx[r] = fmaxf(mx[r], colv[j] ? acc[i][j][r] : -3e38f);
            #pragma unroll
            for (int r = 0; r < 4; ++r) {
                float mm = mx[r];
                #pragma unroll
                for (int off = 1; off <= 8; off <<= 1) mm = fmaxf(mm, __shfl_xor(mm, off, 64));
                if (m16 == 0) {
                    int R = rowA0 + i * 16 + q * 4 + r;
                    if (R < M_) {
                        int x = R / NA_, a = R - x * NA_;
                        maxvisH[((((size_t)x * B_ + y) * NA_ + a) * T_ + t) * 2 + half] = mm;
                    }
                }
            }
        }
    }

    // ---- one atomic per wave for the clip-sum ----
    #pragma unroll
    for (int off = 32; off; off >>= 1) cs += __shfl_xor(cs, off, 64);
    if (lane == 0) atomicAdd(accNonneg, cs);
}

// ---------------- per-(x,y) aggregation over (a,t); folds the 2 col-halves ----
__global__ void aggregate_kernel(const float* __restrict__ maxvisH,
                                 const float* __restrict__ thrPtr,
                                 const float* __restrict__ scalePtr,
                                 float* __restrict__ clipSims,
                                 float* __restrict__ accFrac,
                                 float* __restrict__ accSel)
{
    int xy = blockIdx.x;
    int x = xy / B_, y = xy % B_;
    int a = threadIdx.x;
    float th    = 1.0f / (1.0f + expf(-thrPtr[0]));
    float scale = scalePtr[0];
    float token = 0.0f, cnt = 0.0f, selsum = 0.0f;
    if (a < NA_) {
        const float* p = maxvisH + ((((size_t)x * B_ + y) * NA_ + a) * T_) * 2;
        float ws = 0.0f, ss = 0.0f;
        #pragma unroll
        for (int t = 0; t < T_; ++t) {
            float mv  = fmaxf(p[2 * t], p[2 * t + 1]);
            float rd  = mv - th;
            float sel = fmaxf(rd, 0.0f) * scale;
            ws += mv * sel;
            ss += sel;
            if (rd > 0.0f) cnt += 1.0f;
            if (x == y) selsum += 0.5f * (tanhf(20.0f * rd) + 1.0f);
        }
        token = ws / fmaxf(ss, 1e-6f);
    }
    #pragma unroll
    for (int off = 32; off; off >>= 1) {
        token  += __shfl_xor(token,  off, 64);
        cnt    += __shfl_xor(cnt,    off, 64);
        selsum += __shfl_xor(selsum, off, 64);
    }
    if (threadIdx.x == 0) {
        clipSims[x * B_ + y] = token / (float)NA_;
        atomicAdd(accFrac, cnt);
        if (x == y) atomicAdd(accSel, selsum);
    }
}

// ---------------- finalize ----------------
__global__ void finalize_kernel(const float* __restrict__ clipSims,
                                const float* __restrict__ accs,
                                const float* __restrict__ tempPtr,
                                const float* __restrict__ scalePtr,
                                const float* __restrict__ thrPtr,
                                float* __restrict__ out)
{
    __shared__ float cs[B_ * B_];
    int tid = threadIdx.x;  // 64
    for (int i = tid; i < B_ * B_; i += 64) cs[i] = clipSims[i];
    __syncthreads();
    float lsum = 0.0f;
    if (tid < B_) {
        int i = tid;
        float m = -1e30f;
        for (int j = 0; j < B_; ++j) m = fmaxf(m, cs[i * B_ + j]);
        float e = 0.0f;
        for (int j = 0; j < B_; ++j) e += expf(cs[i * B_ + j] - m);
        float la = m + logf(e) - cs[i * B_ + i];
        float m2 = -1e30f;
        for (int j = 0; j < B_; ++j) m2 = fmaxf(m2, cs[j * B_ + i]);
        float e2 = 0.0f;
        for (int j = 0; j < B_; ++j) e2 += expf(cs[j * B_ + i] - m2);
        float lv = m2 + logf(e2) - cs[i * B_ + i];
        lsum = la + lv;
    }
    #pragma unroll
    for (int off = 32; off; off >>= 1) lsum += __shfl_xor(lsum, off, 64);
    if (tid == 0) {
        float contrastive = lsum / (float)B_ * 0.5f;
        float temp = tempPtr[0], scl = scalePtr[0];
        float th = 1.0f / (1.0f + expf(-thrPtr[0]));
        float l_nonneg = accs[0] / 56448000.0f;   // B*B*NA*T*NV
        float logt = logf(temp);
        float tl  = fmaxf(-logt, 0.0f);
        float thi = fmaxf(logt - logf(4.0f), 0.0f);
        float l_cal = tl * tl + thi * thi;
        float t1 = fmaxf(th - 0.9f, 0.0f), t2 = fmaxf(0.1f - th, 0.0f);
        float l_thr = t1 * t1 + t2 * t2;
        float s1 = fmaxf(scl - 20.0f, 0.0f), s2 = fmaxf(1.0f - scl, 0.0f);
        float l_scale = s1 * s1 + s2 * s2;
        float reg = 0.15f * l_nonneg + 2.0f * l_cal + 0.1f * l_thr + 0.1f * l_scale;
        float frac   = accs[1] / 288000.0f;       // B*B*NA*T
        float selrew = -0.1f * log1pf(accs[2] / 12000.0f); // B*NA*T
        out[0] = selrew + contrastive + reg;
        out[1] = contrastive;
        out[2] = reg;
        out[3] = frac;
        out[4] = selrew;
    }
}

extern "C" void kernel_launch(void* const* d_in, const int* in_sizes, int n_in,
                              void* d_out, int out_size, void* d_ws, size_t ws_size,
                              hipStream_t stream) {
    const float* audio  = (const float*)d_in[0];  // (24,50,512)
    const float* visual = (const float*)d_in[1];  // (24,10,196,512)
    const float* temp   = (const float*)d_in[2];
    const float* scale  = (const float*)d_in[3];
    const float* thr    = (const float*)d_in[4];
    float* out = (float*)d_out;

    unsigned char* wsb = (unsigned char*)d_ws;
    unsigned short* Abf = (unsigned short*)wsb;                       // 1280*512*2  = 1,310,720 B
    unsigned short* Vbf = (unsigned short*)(wsb + 1310720);           // 53760*512*2 = 55,050,240 B
    float* maxvisH  = (float*)(wsb + 1310720 + 55050240);             // 576000 floats = 2,304,000 B
    float* clipSims = (float*)(wsb + 1310720 + 55050240 + 2304000);   // 576 floats
    float* accs     = clipSims + 576;                                 // 3: [nonneg, frac, sel]

    normconv_kernel<<<(VROWS + MPAD) / 4, 256, 0, stream>>>(visual, audio, temp, Vbf, Abf, accs);

    simred_kernel<<<480, 256, 0, stream>>>(Abf, Vbf, maxvisH, accs);

    aggregate_kernel<<<B_ * B_, 64, 0, stream>>>(maxvisH, thr, scale, clipSims, accs + 1, accs + 2);
    finalize_kernel<<<1, 64, 0, stream>>>(clipSims, accs, temp, scale, thr, out);
}